// Round 5
// baseline (199.219 us; speedup 1.0000x reference)
//
#include <hip/hip_runtime.h>
#include <cstdint>

#define NB 64
#define NC 256
#define ND 256
#define NT 4096

#define BT 64                    // t-columns per tile
#define NTILES 16                // tiles per block
#define CHUNK (BT * NTILES)      // 1024 t per block
#define NCHUNK (NT / CHUNK)      // 4 chunks -> 256 blocks = 1 per CU

typedef __attribute__((ext_vector_type(8)))  _Float16 half8;
typedef __attribute__((ext_vector_type(16))) float    f32x16;

union FragA { uint32_t u[4]; uint4 q; half8 v; };

__device__ __forceinline__ uint32_t pk_f16(float lo, float hi) {
    // v_cvt_pkrtz_f16_f32: D.lo=f16(lo), D.hi=f16(hi) — matches MFMA (k even, k odd) packing
    return __builtin_bit_cast(uint32_t, __builtin_amdgcn_cvt_pkrtz(lo, hi));
}

// Raw barrier WITHOUT the __syncthreads vmcnt(0) drain: LDS ops complete
// (lgkmcnt(0)) but global stores/loads stay in flight across the barrier
// (T4: never drain vmcnt in the main loop). Memory clobbers fence the
// compiler: ds_writes can't sink below, ds_reads can't hoist above.
__device__ __forceinline__ void block_sync_lds() {
    asm volatile("s_waitcnt lgkmcnt(0)" ::: "memory");
    __builtin_amdgcn_s_barrier();
    asm volatile("" ::: "memory");
}

// LDS layout (per buffer): fp16 x-tile, [t=0..63][c=0..255], row = 512 B.
// byte(t, c) = t*512 + ( (2*c) ^ ((t&15)<<4) )   — XOR swizzle on 16B columns,
// applied identically on write and read (involution within each 512B row).
//
// MFMA orientation: D[m=d][n=t] = sum_c W^T[d][c] * X[c][t]
//   A-operand = W fragment (lane&31 = d, k = 8*(lane>>5)+j)
//   B-operand = X fragment (lane&31 = t, k = 8*(lane>>5)+j)
//   C/D: col = lane&31 = t  -> stores are 4B/lane coalesced
__global__ __launch_bounds__(1024)
void subject_gemm(const float* __restrict__ x,
                  const int*   __restrict__ subjects,
                  const float* __restrict__ w,
                  float*       __restrict__ out)
{
    __shared__ __align__(16) unsigned char lds[2 * 64 * 512];   // 64 KiB, double-buffered

    const int tid  = threadIdx.x;
    const int lane = tid & 63;
    const int wv   = tid >> 6;      // 0..15
    const int wd   = wv & 7;        // d-range (32 d per wave)
    const int wm   = wv >> 3;       // t-half (32 t per wave)
    const int g    = lane >> 5;     // k-group
    const int l31  = lane & 31;
    const int b    = blockIdx.y;
    const int t0   = blockIdx.x * CHUNK;

    const int sub = subjects[b];
    const float* __restrict__ wsub = w + (size_t)sub * NC * ND;
    const float* __restrict__ xb   = x + (size_t)b * NC * NT;
    float*       __restrict__ ob   = out + (size_t)b * ND * NT;

    const int dlane = wd * 32 + l31;

    // ---- one-time: W fragments (fp16) in registers; lane&31 = d, k(c) = 8*g+j ----
    half8 wf[16];
#pragma unroll
    for (int ks = 0; ks < 16; ++ks) {
        float f[8];
#pragma unroll
        for (int j = 0; j < 8; ++j)
            f[j] = wsub[(size_t)(ks * 16 + g * 8 + j) * ND + dlane];
        FragA tmp;
#pragma unroll
        for (int p = 0; p < 4; ++p) tmp.u[p] = pk_f16(f[2 * p], f[2 * p + 1]);
        wf[ks] = tmp.v;
    }

    // ---- staging assignment: wave wv owns c in [wv*16, wv*16+16), lane = t ----
    const int cbase = wv * 16;
    const uint32_t wr_swz   = ((uint32_t)(lane & 15)) << 4;
    const uint32_t wr_byte0 = (uint32_t)lane * 512 + (((uint32_t)cbase * 2 +  0) ^ wr_swz);
    const uint32_t wr_byte1 = (uint32_t)lane * 512 + (((uint32_t)cbase * 2 + 16) ^ wr_swz);

    // read-side constants: t_local = wm*32 + l31
    const int      trd    = wm * 32 + l31;
    const uint32_t rd_swz = ((uint32_t)(trd & 15)) << 4;
    const uint32_t rd_row = (uint32_t)trd * 512;

    const float* xg = xb + (size_t)cbase * NT + t0 + lane;   // + i*NT + tile*BT

    float stage[16];

    // prologue: stage tile 0
#pragma unroll
    for (int i = 0; i < 16; ++i) stage[i] = xg[(size_t)i * NT];
    {
        uint4 q0, q1;
        q0.x = pk_f16(stage[0],  stage[1]);  q0.y = pk_f16(stage[2],  stage[3]);
        q0.z = pk_f16(stage[4],  stage[5]);  q0.w = pk_f16(stage[6],  stage[7]);
        q1.x = pk_f16(stage[8],  stage[9]);  q1.y = pk_f16(stage[10], stage[11]);
        q1.z = pk_f16(stage[12], stage[13]); q1.w = pk_f16(stage[14], stage[15]);
        *reinterpret_cast<uint4*>(&lds[wr_byte0]) = q0;
        *reinterpret_cast<uint4*>(&lds[wr_byte1]) = q1;
    }
    block_sync_lds();

    for (int tile = 0; tile < NTILES; ++tile) {
        const uint32_t bufoff = (uint32_t)(tile & 1) * 32768;

        // T14 issue-early: next tile's 16 global loads FIRST, pinned by a
        // sched_barrier so the compiler cannot sink them toward their use.
        if (tile + 1 < NTILES) {
            const float* src = xg + (size_t)(tile + 1) * BT;
#pragma unroll
            for (int i = 0; i < 16; ++i) stage[i] = src[(size_t)i * NT];
            __builtin_amdgcn_sched_barrier(0);
        }

        // ---- compute: one 32(d) x 32(t) tile per wave, K=256 in 16 MFMA steps ----
        f32x16 acc = {};
#pragma unroll
        for (int ks = 0; ks < 16; ++ks) {
            const uint32_t colb = ((uint32_t)(ks * 32 + g * 16)) ^ rd_swz;
            FragA a;
            a.q = *reinterpret_cast<const uint4*>(&lds[bufoff + rd_row + colb]);
            acc = __builtin_amdgcn_mfma_f32_32x32x16_f16(wf[ks], a.v, acc, 0, 0, 0);
        }

        // ---- store: col = lane&31 = t ; row d = (reg&3) + 8*(reg>>2) + 4*g ----
        // issued BEFORE the cvt's load-wait so they're in flight early; they
        // drain lazily (no vmcnt(0) anywhere in this loop).
        const int tcol = t0 + tile * BT + wm * 32;
#pragma unroll
        for (int rg = 0; rg < 16; ++rg) {
            const int drow = wd * 32 + (rg & 3) + 8 * (rg >> 2) + 4 * g;
            ob[(size_t)drow * NT + tcol + l31] = acc[rg];
        }

        // convert + write staged tile (compiler inserts counted vmcnt: waits the
        // 16 loads, leaves the 16 stores outstanding)
        if (tile + 1 < NTILES) {
            const uint32_t nb = (uint32_t)((tile + 1) & 1) * 32768;
            uint4 q0, q1;
            q0.x = pk_f16(stage[0],  stage[1]);  q0.y = pk_f16(stage[2],  stage[3]);
            q0.z = pk_f16(stage[4],  stage[5]);  q0.w = pk_f16(stage[6],  stage[7]);
            q1.x = pk_f16(stage[8],  stage[9]);  q1.y = pk_f16(stage[10], stage[11]);
            q1.z = pk_f16(stage[12], stage[13]); q1.w = pk_f16(stage[14], stage[15]);
            *reinterpret_cast<uint4*>(&lds[nb + wr_byte0]) = q0;
            *reinterpret_cast<uint4*>(&lds[nb + wr_byte1]) = q1;
        }
        block_sync_lds();
    }
}

extern "C" void kernel_launch(void* const* d_in, const int* in_sizes, int n_in,
                              void* d_out, int out_size, void* d_ws, size_t ws_size,
                              hipStream_t stream)
{
    const float* x        = (const float*)d_in[0];
    const int*   subjects = (const int*)d_in[1];
    const float* w        = (const float*)d_in[2];
    float*       out      = (float*)d_out;

    dim3 grid(NCHUNK, NB);   // 4 x 64 = 256 blocks, 1024 threads, 64 KiB LDS
    subject_gemm<<<grid, 1024, 0, stream>>>(x, subjects, w, out);
}

// Round 7
// 126.422 us; speedup vs baseline: 1.5758x; 1.5758x over previous
//
#include <hip/hip_runtime.h>
#include <cstdint>

#define NB 64
#define NC 256
#define ND 256
#define NT 4096

#define BT 32                    // t-columns per tile
#define NTILES 16                // tiles per block
#define CHUNK (BT * NTILES)      // 512 t per block
#define NCHUNK (NT / CHUNK)      // 8 chunks -> 512 blocks = 2 per CU

typedef __attribute__((ext_vector_type(8)))  _Float16 half8;
typedef __attribute__((ext_vector_type(16))) float    f32x16;

union FragA { uint32_t u[4]; uint4 q; half8 v; };

__device__ __forceinline__ uint32_t pk_f16(float lo, float hi) {
    // v_cvt_pkrtz_f16_f32: D.lo=f16(lo), D.hi=f16(hi) — matches MFMA (k even, k odd) packing
    return __builtin_bit_cast(uint32_t, __builtin_amdgcn_cvt_pkrtz(lo, hi));
}

// Structure: 512-thread blocks (8 waves), each wave owns d in [wv*32, wv*32+32),
// block covers full d=0..255 for a 512-t chunk in 16 tiles of BT=32.
// 2 blocks/CU (32 KiB LDS, <=128 VGPR via __launch_bounds__(512,4)): while one
// block drains at its barrier, the other streams — TLP covers the drain.
//
// Sync: plain __syncthreads() (full vmcnt+lgkm drain + compiler fence).
// R6's lgkm-only inline-asm barrier raced under 2-block/CU replay timing
// (post-timing absmax 1.2) — m152 lesson: custom sync needs a race-screen;
// revert to the builtin and buy overlap with occupancy instead.
//
// LDS (per buffer, 16 KiB): fp16 x-tile [t=0..31][c=0..255], row = 512 B,
// byte(t,c) = t*512 + ((2c) ^ ((t&15)<<4))  — XOR swizzle, same on write & read.
//
// MFMA: D[m=d][n=t] = sum_c W^T[d][c] * X[c][t]
//   A = W frag (lane&31 = d, k = 8*(lane>>5)+j), B = x frag (lane&31 = t)
//   C/D: col = lane&31 = t -> coalesced 4B/lane stores.
__global__ __launch_bounds__(512, 4)
void subject_gemm(const float* __restrict__ x,
                  const int*   __restrict__ subjects,
                  const float* __restrict__ w,
                  float*       __restrict__ out)
{
    __shared__ __align__(16) unsigned char lds[2 * 32 * 512];   // 32 KiB total

    const int tid  = threadIdx.x;
    const int lane = tid & 63;
    const int wv   = tid >> 6;      // 0..7 : d-subtile
    const int g    = lane >> 5;     // k-group / c-half
    const int l31  = lane & 31;     // t within tile (and d within subtile for W)
    const int b    = blockIdx.y;
    const int t0   = blockIdx.x * CHUNK;

    const int sub = subjects[b];
    const float* __restrict__ wsub = w + (size_t)sub * NC * ND;
    const float* __restrict__ xb   = x + (size_t)b * NC * NT;
    float*       __restrict__ ob   = out + (size_t)b * ND * NT;

    const int dlane = wv * 32 + l31;

    // ---- one-time: W fragments (fp16) in registers; lane&31 = d, k(c) = 8g+j ----
    half8 wf[16];
#pragma unroll
    for (int ks = 0; ks < 16; ++ks) {
        float f[8];
#pragma unroll
        for (int j = 0; j < 8; ++j)
            f[j] = wsub[(size_t)(ks * 16 + g * 8 + j) * ND + dlane];
        FragA tmp;
#pragma unroll
        for (int p = 0; p < 4; ++p) tmp.u[p] = pk_f16(f[2 * p], f[2 * p + 1]);
        wf[ks] = tmp.v;
    }

    // ---- staging: thread owns c in [c0, c0+16), t = l31 ----
    const int c0 = wv * 32 + g * 16;
    const uint32_t swz      = ((uint32_t)(l31 & 15)) << 4;
    const uint32_t wr_byte0 = (uint32_t)l31 * 512 + (((uint32_t)c0 * 2 +  0) ^ swz);
    const uint32_t wr_byte1 = (uint32_t)l31 * 512 + (((uint32_t)c0 * 2 + 16) ^ swz);
    const uint32_t rd_row   = (uint32_t)l31 * 512;

    const float* xg = xb + (size_t)c0 * NT + t0 + l31;   // + i*NT + tile*BT

    float stage[16];

    // prologue: stage tile 0
#pragma unroll
    for (int i = 0; i < 16; ++i) stage[i] = xg[(size_t)i * NT];
    {
        uint4 q0, q1;
        q0.x = pk_f16(stage[0],  stage[1]);  q0.y = pk_f16(stage[2],  stage[3]);
        q0.z = pk_f16(stage[4],  stage[5]);  q0.w = pk_f16(stage[6],  stage[7]);
        q1.x = pk_f16(stage[8],  stage[9]);  q1.y = pk_f16(stage[10], stage[11]);
        q1.z = pk_f16(stage[12], stage[13]); q1.w = pk_f16(stage[14], stage[15]);
        *reinterpret_cast<uint4*>(&lds[wr_byte0]) = q0;
        *reinterpret_cast<uint4*>(&lds[wr_byte1]) = q1;
    }
    __syncthreads();

    for (int tile = 0; tile < NTILES; ++tile) {
        const uint32_t bufoff = (uint32_t)(tile & 1) * 16384;

        // issue next tile's 16 global loads first; pin them above compute
        if (tile + 1 < NTILES) {
            const float* src = xg + (size_t)(tile + 1) * BT;
#pragma unroll
            for (int i = 0; i < 16; ++i) stage[i] = src[(size_t)i * NT];
            __builtin_amdgcn_sched_barrier(0);
        }

        // ---- compute: 32(d) x 32(t) per wave, K=256 in 16 MFMA steps ----
        f32x16 acc = {};
#pragma unroll
        for (int ks = 0; ks < 16; ++ks) {
            const uint32_t colb = ((uint32_t)(ks * 32 + g * 16)) ^ swz;
            FragA a;
            a.q = *reinterpret_cast<const uint4*>(&lds[bufoff + rd_row + colb]);
            acc = __builtin_amdgcn_mfma_f32_32x32x16_f16(wf[ks], a.v, acc, 0, 0, 0);
        }

        // ---- store: col = lane&31 = t ; row d = (reg&3) + 8*(reg>>2) + 4*g ----
        const int tcol = t0 + tile * BT;
#pragma unroll
        for (int rg = 0; rg < 16; ++rg) {
            const int drow = wv * 32 + (rg & 3) + 8 * (rg >> 2) + 4 * g;
            ob[(size_t)drow * NT + tcol + l31] = acc[rg];
        }

        // convert + ds_write staged tile into the other buffer
        if (tile + 1 < NTILES) {
            const uint32_t nb = (uint32_t)((tile + 1) & 1) * 16384;
            uint4 q0, q1;
            q0.x = pk_f16(stage[0],  stage[1]);  q0.y = pk_f16(stage[2],  stage[3]);
            q0.z = pk_f16(stage[4],  stage[5]);  q0.w = pk_f16(stage[6],  stage[7]);
            q1.x = pk_f16(stage[8],  stage[9]);  q1.y = pk_f16(stage[10], stage[11]);
            q1.z = pk_f16(stage[12], stage[13]); q1.w = pk_f16(stage[14], stage[15]);
            *reinterpret_cast<uint4*>(&lds[nb + wr_byte0]) = q0;
            *reinterpret_cast<uint4*>(&lds[nb + wr_byte1]) = q1;
        }
        __syncthreads();
    }
}

extern "C" void kernel_launch(void* const* d_in, const int* in_sizes, int n_in,
                              void* d_out, int out_size, void* d_ws, size_t ws_size,
                              hipStream_t stream)
{
    const float* x        = (const float*)d_in[0];
    const int*   subjects = (const int*)d_in[1];
    const float* w        = (const float*)d_in[2];
    float*       out      = (float*)d_out;

    dim3 grid(NCHUNK, NB);   // 8 x 64 = 512 blocks of 512 threads = 2 per CU
    subject_gemm<<<grid, 512, 0, stream>>>(x, subjects, w, out);
}